// Round 4
// baseline (29009.326 us; speedup 1.0000x reference)
//
#include <hip/hip_runtime.h>

typedef __bf16 bf16;
typedef __bf16 bf16x8 __attribute__((ext_vector_type(8)));
typedef float  f32x4  __attribute__((ext_vector_type(4)));
typedef unsigned int u32x4 __attribute__((ext_vector_type(4)));

#define B_TOT 4096
#define T_SEQ 64
#define F_IN  32
#define C_CTY 64
#define L_LAT 256
#define W_HID 512
#define NT_OUT 8
#define SUBSTEPS 10
#define MB   16      // batch rows per block
#define NBLK 256     // one block per CU
#define NTHR 1024    // 16 waves

// Tsit5 tableau
constexpr float A21 = 0.161f;
constexpr float A31 = -0.008480655492356989f, A32 = 0.335480655492357f;
constexpr float A41 = 2.8971530571054935f, A42 = -6.359448489975075f, A43 = 4.362295432869581f;
constexpr float A51 = 5.325864828439257f, A52 = -11.748883564062828f, A53 = 7.4955393428898365f, A54 = -0.09249506636175525f;
constexpr float A61 = 5.86145544294642f, A62 = -12.92096931784711f, A63 = 8.159367898576159f, A64 = -0.071584973281401f, A65 = -0.028269050394068383f;
constexpr float BC1 = 0.09646076681806523f, BC2 = 0.01f, BC3 = 0.4798896504144996f;
constexpr float BC4 = 1.379008574103742f, BC5 = -3.290069515436081f, BC6 = 2.324710524099774f;
constexpr float DT = 0.1f;
constexpr float BROW[5][5] = {
    {A21, 0, 0, 0, 0},
    {A31, A32, 0, 0, 0},
    {A41, A42, A43, 0, 0},
    {A51, A52, A53, A54, 0},
    {A61, A62, A63, A64, A65}};
constexpr float FCF[6] = {BC1, BC2, BC3, BC4, BC5, BC6};

__device__ __forceinline__ f32x4 MFMA(bf16x8 a, bf16x8 b, f32x4 c) {
    return __builtin_amdgcn_mfma_f32_16x16x32_bf16(a, b, c, 0, 0, 0);
}
__device__ __forceinline__ float eluf(float x) { return x > 0.f ? x : __expf(x) - 1.f; }
__device__ __forceinline__ float sigm_f(float x) { return 1.f / (1.f + __expf(-x)); }
__device__ __forceinline__ float tanh_f(float x) { return 1.f - 2.f / (__expf(2.f * x) + 1.f); }

// Pin a weight fragment into an AGPR quad: the asm output cannot be
// rematerialized, so the value stays register-resident across the main loop.
// (MFMA A/B operands may be AGPRs on gfx950 — ISA §10.)
__device__ __forceinline__ void pinA(bf16x8& x) {
    u32x4 t = __builtin_bit_cast(u32x4, x);
    asm volatile("" : "+a"(t));
    x = __builtin_bit_cast(bf16x8, t);
}
__device__ __forceinline__ void pinV(float& x) { asm volatile("" : "+v"(x)); }

// scatter addr (elems) for value (feat n = w*16+lm, batch b) into 8-frag A-linear buffer
__device__ __forceinline__ int dpos16(int w, int lm, int b) {
    return ((w >> 1) * 64 + (2 * (w & 1) + (lm >> 3)) * 16 + b) * 8 + (lm & 7);
}
// scatter addr for value (feat n = (2w+nt)*16+lm, batch b) into 16-frag A-linear buffer
__device__ __forceinline__ int dpos32(int w, int nt, int lm, int b) {
    return (w * 64 + (2 * nt + (lm >> 3)) * 16 + b) * 8 + (lm & 7);
}

// ---- one Tsit5 stage (3 layers, 3 barriers), weights in AGPRs ----
template<int STAGE>
__device__ __forceinline__ void ode_stage(
    bf16* __restrict__ Yb, bf16* __restrict__ Ab, bf16* __restrict__ Bb,
    float* __restrict__ Ydec,
    const bf16x8 (&w0r)[2][8], const bf16x8 (&w1r)[2][16], const bf16x8 (&w2r)[16],
    const float (&b0r)[2], const float (&b1r)[2], float b2r,
    f32x4& yreg, f32x4 (&kreg)[6], int w, int lane, bool dec) {
    const int lm = lane & 15, q4 = (lane >> 4) << 2;
    const f32x4 z = {0.f, 0.f, 0.f, 0.f};

    // ---- L0: h1 = elu(y_stage @ W0^T + b0): read Yb (8 frags), write Ab ----
    f32x4 acc0[2] = {z, z};
    {
        bf16x8 a[8];
        #pragma unroll
        for (int kk = 0; kk < 8; ++kk) a[kk] = *(const bf16x8*)&Yb[(kk * 64 + lane) * 8];
        #pragma unroll
        for (int kk = 0; kk < 8; ++kk) {
            acc0[0] = MFMA(a[kk], w0r[0][kk], acc0[0]);
            acc0[1] = MFMA(a[kk], w0r[1][kk], acc0[1]);
        }
    }
    #pragma unroll
    for (int nt = 0; nt < 2; ++nt)
        #pragma unroll
        for (int r = 0; r < 4; ++r)
            Ab[dpos32(w, nt, lm, q4 + r)] = (bf16)eluf(acc0[nt][r] + b0r[nt]);
    __syncthreads();

    // ---- L1: h2 = elu(h1 @ W1^T + b1): read Ab (16 frags), write Bb ----
    f32x4 acc1[2] = {z, z};
    #pragma unroll
    for (int h2 = 0; h2 < 2; ++h2) {
        bf16x8 a[8];
        #pragma unroll
        for (int kk = 0; kk < 8; ++kk) a[kk] = *(const bf16x8*)&Ab[((h2 * 8 + kk) * 64 + lane) * 8];
        #pragma unroll
        for (int kk = 0; kk < 8; ++kk) {
            acc1[0] = MFMA(a[kk], w1r[0][h2 * 8 + kk], acc1[0]);
            acc1[1] = MFMA(a[kk], w1r[1][h2 * 8 + kk], acc1[1]);
        }
    }
    #pragma unroll
    for (int nt = 0; nt < 2; ++nt)
        #pragma unroll
        for (int r = 0; r < 4; ++r)
            Bb[dpos32(w, nt, lm, q4 + r)] = (bf16)eluf(acc1[nt][r] + b1r[nt]);
    __syncthreads();

    // ---- L2: k = h2 @ W2^T + b2: read Bb (16 frags) -> kreg; build y_stage -> Yb ----
    f32x4 acc2 = z;
    #pragma unroll
    for (int h2 = 0; h2 < 2; ++h2) {
        bf16x8 a[8];
        #pragma unroll
        for (int kk = 0; kk < 8; ++kk) a[kk] = *(const bf16x8*)&Bb[((h2 * 8 + kk) * 64 + lane) * 8];
        #pragma unroll
        for (int kk = 0; kk < 8; ++kk) acc2 = MFMA(a[kk], w2r[h2 * 8 + kk], acc2);
    }
    #pragma unroll
    for (int r = 0; r < 4; ++r) kreg[STAGE][r] = acc2[r] + b2r;

    f32x4 yst;
    if constexpr (STAGE < 5) {
        yst = yreg;
        #pragma unroll
        for (int i = 0; i <= STAGE; ++i) {
            const float c = DT * BROW[STAGE][i];
            #pragma unroll
            for (int r = 0; r < 4; ++r) yst[r] += c * kreg[i][r];
        }
    } else {
        #pragma unroll
        for (int i = 0; i < 6; ++i) {
            const float c = DT * FCF[i];
            #pragma unroll
            for (int r = 0; r < 4; ++r) yreg[r] += c * kreg[i][r];
        }
        yst = yreg;
        if (dec) {
            #pragma unroll
            for (int r = 0; r < 4; ++r)
                Ydec[(q4 + r) * 260 + w * 16 + lm] = yreg[r];
        }
    }
    #pragma unroll
    for (int r = 0; r < 4; ++r)
        Yb[dpos16(w, lm, q4 + r)] = (bf16)yst[r];
    __syncthreads();
}

__global__ void __launch_bounds__(NTHR, 4)
k_main(const float* __restrict__ x_seq, const int* __restrict__ cidx,
       const float* __restrict__ b_n, const float* __restrict__ b0,
       const float* __restrict__ b1, const float* __restrict__ b2,
       const float* __restrict__ W_dec, const float* __restrict__ b_dec,
       const bf16* __restrict__ WihP, const bf16* __restrict__ WhhP,
       const bf16* __restrict__ W0p, const bf16* __restrict__ W1p,
       const bf16* __restrict__ W2p, const float* __restrict__ bias_c,
       float* __restrict__ out, int H) {
    __shared__ __align__(16) bf16 sYb[8 * 512];        // y_stage frags
    __shared__ __align__(16) bf16 sAb[16 * 512];       // h1 frags
    __shared__ __align__(16) bf16 sBb[16 * 512];       // h2 frags
    __shared__ __align__(16) bf16 sHx[2 * 9 * 512];    // GRU [h|x] frags, dbuf
    __shared__ __align__(16) float sYdec[MB * 260];    // f32 y for decode
    __shared__ __align__(16) float sWdec[NT_OUT * L_LAT];
    __shared__ float sBdec[NT_OUT];

    const int tid = threadIdx.x, w = tid >> 6, lane = tid & 63;
    const int lm = lane & 15, q = lane >> 4, q4 = q << 2;
    const int b0row = blockIdx.x * MB;

    for (int i = tid; i < NT_OUT * L_LAT; i += NTHR) sWdec[i] = W_dec[i];
    if (tid < NT_OUT) sBdec[tid] = b_dec[tid];

    // ---------- GRU phase: weights + gate biases in registers ----------
    const int nf = w * 16 + lm;                        // this lane's feature
    float bcr[4], bcz[4], bcn[4];
    {
        #pragma unroll
        for (int r = 0; r < 4; ++r) {
            const int c = cidx[b0row + q4 + r];
            bcr[r] = bias_c[(size_t)c * 768 + nf];
            bcz[r] = bias_c[(size_t)c * 768 + 256 + nf];
            bcn[r] = bias_c[(size_t)c * 768 + 512 + nf];
            pinV(bcr[r]); pinV(bcz[r]); pinV(bcn[r]);
        }
    }
    float bnr = b_n[nf];
    pinV(bnr);

    bf16x8 whr[3][8], wxr[3];
    {
        const int tiles[3] = {w, 16 + w, 32 + w};
        #pragma unroll
        for (int j = 0; j < 3; ++j) {
            wxr[j] = *(const bf16x8*)&WihP[(size_t)tiles[j] * 512 + lane * 8];
            pinA(wxr[j]);
            #pragma unroll
            for (int kk = 0; kk < 8; ++kk) {
                whr[j][kk] = *(const bf16x8*)&WhhP[((size_t)tiles[j] * 8 + kk) * 512 + lane * 8];
                pinA(whr[j][kk]);
            }
        }
    }

    f32x4 hreg = {0.f, 0.f, 0.f, 0.f};
    f32x4 xra = {0.f, 0.f, 0.f, 0.f}, xrb = {0.f, 0.f, 0.f, 0.f};

    // prologue: scatter h=0 into buf0; wave15 stages x(0), prefetches x(1)
    if (w == 15) {
        const float* xs = &x_seq[((size_t)(b0row + (lane & 15)) * T_SEQ + 0) * F_IN + 8 * q];
        xra = *(const f32x4*)xs;
        xrb = *(const f32x4*)(xs + 4);
    }
    #pragma unroll
    for (int r = 0; r < 4; ++r) sHx[dpos16(w, lm, q4 + r)] = (bf16)0.f;
    if (w == 15) {
        bf16x8 ox;
        #pragma unroll
        for (int j = 0; j < 4; ++j) { ox[j] = (bf16)xra[j]; ox[4 + j] = (bf16)xrb[j]; }
        *(bf16x8*)&sHx[(8 * 64 + lane) * 8] = ox;
        const float* xs = &x_seq[((size_t)(b0row + (lane & 15)) * T_SEQ + 1) * F_IN + 8 * q];
        xra = *(const f32x4*)xs;
        xrb = *(const f32x4*)(xs + 4);
    }

    for (int t = 0; t < T_SEQ; ++t) {
        const bf16* hx = sHx + (t & 1) * (9 * 512);
        __syncthreads();
        bf16x8 a[9];
        #pragma unroll
        for (int kk = 0; kk < 9; ++kk) a[kk] = *(const bf16x8*)&hx[(kk * 64 + lane) * 8];
        const f32x4 z = {0.f, 0.f, 0.f, 0.f};
        f32x4 aH[3] = {z, z, z}, aX[3] = {z, z, z};
        #pragma unroll
        for (int j = 0; j < 3; ++j) aX[j] = MFMA(a[8], wxr[j], aX[j]);
        #pragma unroll
        for (int kk = 0; kk < 8; ++kk)
            #pragma unroll
            for (int j = 0; j < 3; ++j) aH[j] = MFMA(a[kk], whr[j][kk], aH[j]);
        #pragma unroll
        for (int r = 0; r < 4; ++r) {
            const float rg = sigm_f(aH[0][r] + aX[0][r] + bcr[r]);
            const float zg = sigm_f(aH[1][r] + aX[1][r] + bcz[r]);
            const float nn = tanh_f(aX[2][r] + bcn[r] + rg * (aH[2][r] + bnr));
            hreg[r] = nn + zg * (hreg[r] - nn);
        }
        if (t + 1 < T_SEQ) {
            bf16* hxn = sHx + ((t + 1) & 1) * (9 * 512);
            #pragma unroll
            for (int r = 0; r < 4; ++r) hxn[dpos16(w, lm, q4 + r)] = (bf16)hreg[r];
            if (w == 15) {
                bf16x8 ox;
                #pragma unroll
                for (int j = 0; j < 4; ++j) { ox[j] = (bf16)xra[j]; ox[4 + j] = (bf16)xrb[j]; }
                *(bf16x8*)&hxn[(8 * 64 + lane) * 8] = ox;
                const int tn = (t + 2 < T_SEQ) ? t + 2 : T_SEQ - 1;
                const float* xs = &x_seq[((size_t)(b0row + (lane & 15)) * T_SEQ + tn) * F_IN + 8 * q];
                xra = *(const f32x4*)xs;
                xrb = *(const f32x4*)(xs + 4);
            }
        }
    }

    // ---------- load ODE weights into AGPRs (GRU weight AGPRs now dead) ----------
    asm volatile("" ::: "memory");
    bf16x8 w0r[2][8], w1r[2][16], w2r[16];
    #pragma unroll
    for (int nt = 0; nt < 2; ++nt)
        #pragma unroll
        for (int kk = 0; kk < 8; ++kk) {
            w0r[nt][kk] = *(const bf16x8*)&W0p[(((size_t)(2 * w + nt)) * 8 + kk) * 512 + lane * 8];
            pinA(w0r[nt][kk]);
        }
    #pragma unroll
    for (int nt = 0; nt < 2; ++nt)
        #pragma unroll
        for (int kk = 0; kk < 16; ++kk) {
            w1r[nt][kk] = *(const bf16x8*)&W1p[(((size_t)(2 * w + nt)) * 16 + kk) * 512 + lane * 8];
            pinA(w1r[nt][kk]);
        }
    #pragma unroll
    for (int kk = 0; kk < 16; ++kk) {
        w2r[kk] = *(const bf16x8*)&W2p[((size_t)w * 16 + kk) * 512 + lane * 8];
        pinA(w2r[kk]);
    }

    float b0r[2], b1r[2];
    #pragma unroll
    for (int nt = 0; nt < 2; ++nt) {
        b0r[nt] = b0[(2 * w + nt) * 16 + lm];
        b1r[nt] = b1[(2 * w + nt) * 16 + lm];
        pinV(b0r[nt]); pinV(b1r[nt]);
    }
    float b2r = b2[w * 16 + lm];
    pinV(b2r);

    f32x4 yreg = hreg;
    f32x4 kreg[6];
    #pragma unroll
    for (int r = 0; r < 4; ++r)
        sYb[dpos16(w, lm, q4 + r)] = (bf16)yreg[r];
    __syncthreads();

    // ---------- Neural ODE (Tsit5) + decode ----------
    for (int u = 0; u < H; ++u) {
        for (int s = 0; s < SUBSTEPS; ++s) {
            const bool dec = (s == SUBSTEPS - 1);
            ode_stage<0>(sYb, sAb, sBb, sYdec, w0r, w1r, w2r, b0r, b1r, b2r, yreg, kreg, w, lane, false);
            ode_stage<1>(sYb, sAb, sBb, sYdec, w0r, w1r, w2r, b0r, b1r, b2r, yreg, kreg, w, lane, false);
            ode_stage<2>(sYb, sAb, sBb, sYdec, w0r, w1r, w2r, b0r, b1r, b2r, yreg, kreg, w, lane, false);
            ode_stage<3>(sYb, sAb, sBb, sYdec, w0r, w1r, w2r, b0r, b1r, b2r, yreg, kreg, w, lane, false);
            ode_stage<4>(sYb, sAb, sBb, sYdec, w0r, w1r, w2r, b0r, b1r, b2r, yreg, kreg, w, lane, false);
            ode_stage<5>(sYb, sAb, sBb, sYdec, w0r, w1r, w2r, b0r, b1r, b2r, yreg, kreg, w, lane, dec);
        }
        // decode (sYdec written before stage5's final barrier)
        if (tid < MB * NT_OUT) {
            const int m = tid >> 3, tt = tid & 7;
            float acc = sBdec[tt];
            const float* wd = &sWdec[tt * L_LAT];
            #pragma unroll 4
            for (int l = 0; l < L_LAT; l += 4) {
                f32x4 yv = *(const f32x4*)&sYdec[m * 260 + l];
                acc += yv[0] * wd[l] + yv[1] * wd[l + 1] + yv[2] * wd[l + 2] + yv[3] * wd[l + 3];
            }
            out[((size_t)(b0row + m) * H + u) * NT_OUT + tt] = acc;
        }
    }
}

// Pack fp32 weight [OUT][Ksrc] (cols koff..koff+K) into MFMA-fragment order bf16:
// frag f = c*(K/32)+kk; lane's 8 elems = row c*16+(lane&15), k = kk*32+(lane>>4)*8+j
__global__ void k_pack(const float* __restrict__ src, bf16* __restrict__ dst,
                       int OUT, int K, int Ksrc, int koff) {
    const int total = (OUT * K) >> 3;
    for (int g = blockIdx.x * blockDim.x + threadIdx.x; g < total; g += gridDim.x * blockDim.x) {
        const int lane = g & 63, f = g >> 6;
        const int KK = K >> 5;
        const int kk = f % KK, c = f / KK;
        const int col = c * 16 + (lane & 15);
        const int k0 = kk * 32 + ((lane >> 4) << 3);
        bf16x8 o;
        #pragma unroll
        for (int j = 0; j < 8; ++j) o[j] = (bf16)src[(size_t)col * Ksrc + koff + k0 + j];
        *(bf16x8*)&dst[(size_t)g * 8] = o;
    }
}

__global__ void k_bias(const float* __restrict__ W_ih, const float* __restrict__ b_ih,
                       float* __restrict__ bias_c) {
    const int i = blockIdx.x * blockDim.x + threadIdx.x;
    if (i < C_CTY * 3 * L_LAT) {
        const int c = i / (3 * L_LAT), n = i - c * (3 * L_LAT);
        bias_c[i] = W_ih[(size_t)n * (F_IN + C_CTY) + F_IN + c] + b_ih[n];
    }
}

extern "C" void kernel_launch(void* const* d_in, const int* in_sizes, int n_in,
                              void* d_out, int out_size, void* d_ws, size_t ws_size,
                              hipStream_t stream) {
    const float* x_seq = (const float*)d_in[0];
    const int*   cidx  = (const int*)d_in[1];
    const float* W_ih  = (const float*)d_in[3];
    const float* W_hh  = (const float*)d_in[4];
    const float* b_ih  = (const float*)d_in[5];
    const float* b_n   = (const float*)d_in[6];
    const float* W0    = (const float*)d_in[7];
    const float* b0    = (const float*)d_in[8];
    const float* W1    = (const float*)d_in[9];
    const float* b1    = (const float*)d_in[10];
    const float* W2    = (const float*)d_in[11];
    const float* b2    = (const float*)d_in[12];
    const float* W_dec = (const float*)d_in[13];
    const float* b_dec = (const float*)d_in[14];
    float* out = (float*)d_out;
    const int H = out_size / (B_TOT * NT_OUT);

    char* ws = (char*)d_ws;
    bf16*  W0p    = (bf16*)(ws + 0);         // 512*256 bf16 = 262144 B
    bf16*  W1p    = (bf16*)(ws + 262144);    // 512*512      = 524288 B
    bf16*  W2p    = (bf16*)(ws + 786432);    // 256*512      = 262144 B
    bf16*  WhhP   = (bf16*)(ws + 1048576);   // 768*256      = 393216 B
    bf16*  WihP   = (bf16*)(ws + 1441792);   // 768*32       = 49152 B
    float* bias_c = (float*)(ws + 1490944);  // 64*768 f32   = 196608 B

    k_pack<<<64, 256, 0, stream>>>(W0, W0p, 512, 256, 256, 0);
    k_pack<<<128, 256, 0, stream>>>(W1, W1p, 512, 512, 512, 0);
    k_pack<<<64, 256, 0, stream>>>(W2, W2p, 256, 512, 512, 0);
    k_pack<<<96, 256, 0, stream>>>(W_hh, WhhP, 768, 256, 256, 0);
    k_pack<<<12, 256, 0, stream>>>(W_ih, WihP, 768, 32, 96, 0);
    k_bias<<<(C_CTY * 3 * L_LAT + 255) / 256, 256, 0, stream>>>(W_ih, b_ih, bias_c);

    k_main<<<NBLK, NTHR, 0, stream>>>(x_seq, cidx, b_n, b0, b1, b2, W_dec, b_dec,
                                      WihP, WhhP, W0p, W1p, W2p, bias_c, out, H);
}

// Round 5
// 6731.297 us; speedup vs baseline: 4.3096x; 4.3096x over previous
//
#include <hip/hip_runtime.h>

typedef __bf16 bf16;
typedef __bf16 bf16x8 __attribute__((ext_vector_type(8)));
typedef float  f32x4  __attribute__((ext_vector_type(4)));

#define B_TOT 4096
#define T_SEQ 64
#define NT_OUT 8
#define NTHR 512
#define NBLK 256
#define GSZ  8

// ---- ws layout (bytes) ----
#define WS_W0   0           // 512x256 bf16  262144
#define WS_W1   262144      // 512x512 bf16  524288
#define WS_W2   786432      // 256x512 bf16  262144
#define WS_WHH  1048576     // 768x256 bf16  393216
#define WS_WIH  1441792     // 768x32  bf16  49152
#define WS_BC   1490944     // 64x768  f32   196608
#define WS_GY   2097152     // 32 groups x 64KB  (y_stage / GRU h buf0)
#define WS_GYB  4194304     // 32 x 64KB        (GRU h buf1)
#define WS_GH1  6291456     // 32 x 128KB
#define WS_GH2  10485760    // 32 x 128KB
#define WS_FLG  14680064    // 32 x 256B flag blocks
#define WS_MAP  14688256    // 256 u32 xcd map + gctr @ +1024

// Tsit5 tableau
constexpr float A21 = 0.161f;
constexpr float A31 = -0.008480655492356989f, A32 = 0.335480655492357f;
constexpr float A41 = 2.8971530571054935f, A42 = -6.359448489975075f, A43 = 4.362295432869581f;
constexpr float A51 = 5.325864828439257f, A52 = -11.748883564062828f, A53 = 7.4955393428898365f, A54 = -0.09249506636175525f;
constexpr float A61 = 5.86145544294642f, A62 = -12.92096931784711f, A63 = 8.159367898576159f, A64 = -0.071584973281401f, A65 = -0.028269050394068383f;
constexpr float BC1 = 0.09646076681806523f, BC2 = 0.01f, BC3 = 0.4798896504144996f;
constexpr float BC4 = 1.379008574103742f, BC5 = -3.290069515436081f, BC6 = 2.324710524099774f;
constexpr float DT = 0.1f;
constexpr float BROW[5][5] = {
    {A21, 0, 0, 0, 0},
    {A31, A32, 0, 0, 0},
    {A41, A42, A43, 0, 0},
    {A51, A52, A53, A54, 0},
    {A61, A62, A63, A64, A65}};
constexpr float FCF[6] = {BC1, BC2, BC3, BC4, BC5, BC6};

__device__ __forceinline__ f32x4 MFMA(bf16x8 a, bf16x8 b, f32x4 c) {
    return __builtin_amdgcn_mfma_f32_16x16x32_bf16(a, b, c, 0, 0, 0);
}
__device__ __forceinline__ float eluf(float x) { return x > 0.f ? x : __expf(x) - 1.f; }
__device__ __forceinline__ float sigm_f(float x) { return 1.f / (1.f + __expf(-x)); }
__device__ __forceinline__ float tanh_f(float x) { return 1.f - 2.f / (__expf(2.f * x) + 1.f); }

// ---- coherent global access helpers ----
// FAST (group on one XCD): sc0 = bypass L1, read/write shared XCD L2.
// SLOW (cross-XCD group):  sc0 sc1 = reach device coherence point (L3).
template<bool FAST>
__device__ __forceinline__ void ld4g(const bf16* p, bf16x8& a0, bf16x8& a1, bf16x8& a2, bf16x8& a3) {
    if constexpr (FAST) {
        asm volatile(
            "global_load_dwordx4 %0, %4, off sc0\n\t"
            "global_load_dwordx4 %1, %4, off offset:1024 sc0\n\t"
            "global_load_dwordx4 %2, %4, off offset:2048 sc0\n\t"
            "global_load_dwordx4 %3, %4, off offset:3072 sc0"
            : "=&v"(a0), "=&v"(a1), "=&v"(a2), "=&v"(a3)
            : "v"(p) : "memory");
    } else {
        asm volatile(
            "global_load_dwordx4 %0, %4, off sc0 sc1\n\t"
            "global_load_dwordx4 %1, %4, off offset:1024 sc0 sc1\n\t"
            "global_load_dwordx4 %2, %4, off offset:2048 sc0 sc1\n\t"
            "global_load_dwordx4 %3, %4, off offset:3072 sc0 sc1"
            : "=&v"(a0), "=&v"(a1), "=&v"(a2), "=&v"(a3)
            : "v"(p) : "memory");
    }
}
template<bool FAST>
__device__ __forceinline__ bf16x8 ld1g(const bf16* p) {
    bf16x8 a;
    if constexpr (FAST)
        asm volatile("global_load_dwordx4 %0, %1, off sc0\n\ts_waitcnt vmcnt(0)"
                     : "=v"(a) : "v"(p) : "memory");
    else
        asm volatile("global_load_dwordx4 %0, %1, off sc0 sc1\n\ts_waitcnt vmcnt(0)"
                     : "=v"(a) : "v"(p) : "memory");
    return a;
}
template<bool FAST>
__device__ __forceinline__ void st8g(bf16* p, bf16x8 v) {
    if constexpr (FAST) *(bf16x8*)p = v;
    else asm volatile("global_store_dwordx4 %0, %1, off sc0 sc1" :: "v"(p), "v"(v) : "memory");
}
__device__ __forceinline__ void vmwait() {
    asm volatile("s_waitcnt vmcnt(0)" ::: "memory");
    __builtin_amdgcn_sched_barrier(0);
}

// ---- producer/consumer flags (monotone epochs) ----
__device__ __forceinline__ void produce(unsigned* f, int tid) {
    asm volatile("s_waitcnt vmcnt(0)" ::: "memory");   // own wave's stores acked
    __syncthreads();                                   // all waves drained
    if (tid == 0) __hip_atomic_fetch_add(f, 1u, __ATOMIC_RELAXED, __HIP_MEMORY_SCOPE_AGENT);
}
__device__ __forceinline__ void consume(unsigned* f, unsigned tgt, int tid) {
    if (tid == 0) {
        while (__hip_atomic_load(f, __ATOMIC_RELAXED, __HIP_MEMORY_SCOPE_AGENT) < tgt)
            __builtin_amdgcn_s_sleep(8);
    }
    __syncthreads();
}

// ---- decode: rank j emits rows [16j,16j+16) of its group for unit u ----
template<bool FAST>
__device__ __forceinline__ void decode(const bf16* gY, const float* sWdec, const float* sBdec,
                                       float* bncF, float* __restrict__ out,
                                       int tid, int g, int j, int H, int u) {
    {   // phase A: gather y rows (A-frag layout) -> LDS f32 [16][256]
        const int row = tid >> 5, seg = tid & 31;      // seg = kk*4 + octet
        bf16x8 yv = ld1g<FAST>(gY + ((j * 8 + (seg >> 2)) * 64 + row + (seg & 3) * 16) * 8);
        #pragma unroll
        for (int e = 0; e < 8; ++e) bncF[row * 256 + seg * 8 + e] = (float)yv[e];
    }
    __syncthreads();
    if (tid < 128) {
        const int row = tid >> 3, tt = tid & 7;
        float acc = sBdec[tt];
        const float* wd = sWdec + tt * 256;
        const float* yr = bncF + row * 256;
        #pragma unroll 8
        for (int i = 0; i < 256; i += 4) {
            f32x4 yv = *(const f32x4*)&yr[i];
            acc += yv[0] * wd[i] + yv[1] * wd[i + 1] + yv[2] * wd[i + 2] + yv[3] * wd[i + 3];
        }
        out[((size_t)(g * 128 + 16 * j + row) * H + u) * NT_OUT + tt] = acc;
    }
    __syncthreads();   // bounce reused by next stage's scatter
}

// ---- one Tsit5 stage: L0 -> sync -> L1 -> sync -> L2+build -> sync ----
template<int ST, bool FAST>
__device__ __forceinline__ void ode_stage(
    const bf16* sW0, const bf16* sW1, const bf16* sW2, bf16* bnc,
    bf16* gY, bf16* gH1, bf16* gH2,
    unsigned* fY, unsigned* fH1, unsigned* fH2,
    const float (&b0r)[4], const float (&b1r)[4], const float (&b2r)[2],
    f32x4 (&yreg)[2], f32x4 (&kreg)[5][2],
    int tid, int m, int lane, int j,
    unsigned& eY, unsigned& eH1, unsigned& eH2) {
    const int lm = lane & 15, q4 = (lane >> 4) << 2;
    const f32x4 Z = {0.f, 0.f, 0.f, 0.f};

    // ---- L0: h1-slice = elu(y_stage @ W0s^T + b0s) ----
    {
        bf16x8 a[8];
        const bf16* pA = gY + m * 4096 + lane * 8;
        ld4g<FAST>(pA, a[0], a[1], a[2], a[3]);
        ld4g<FAST>(pA + 2048, a[4], a[5], a[6], a[7]);
        vmwait();
        f32x4 acc[4] = {Z, Z, Z, Z};
        #pragma unroll
        for (int kk = 0; kk < 8; ++kk)
            #pragma unroll
            for (int nt = 0; nt < 4; ++nt)
                acc[nt] = MFMA(a[kk], *(const bf16x8*)&sW0[(nt * 8 + kk) * 512 + lane * 8], acc[nt]);
        #pragma unroll
        for (int nt = 0; nt < 4; ++nt) {
            const int oct = 2 * (nt & 1) + (lm >> 3);
            const int base = (m * 2 + (nt >> 1)) * 512;
            #pragma unroll
            for (int r = 0; r < 4; ++r)
                bnc[base + ((q4 + r) + oct * 16) * 8 + (lm & 7)] = (bf16)eluf(acc[nt][r] + b0r[nt]);
        }
    }
    __syncthreads();
    {   // copy 16KB bounce -> gH1 (block's kk slice {2j,2j+1})
        const int i = tid * 16, mm = i >> 10, rem = i & 1023;
        bf16* d = gH1 + mm * 8192 + (2 * j + (rem >> 9)) * 512 + (rem & 511);
        st8g<FAST>(d, *(const bf16x8*)&bnc[i]);
        st8g<FAST>(d + 8, *(const bf16x8*)&bnc[i + 8]);
    }
    produce(fH1, tid); ++eH1;
    consume(fH1, GSZ * eH1, tid);

    // ---- L1: h2-slice = elu(h1 @ W1s^T + b1s) ----
    {
        bf16x8 a[16];
        const bf16* pA = gH1 + m * 8192 + lane * 8;
        ld4g<FAST>(pA, a[0], a[1], a[2], a[3]);
        ld4g<FAST>(pA + 2048, a[4], a[5], a[6], a[7]);
        ld4g<FAST>(pA + 4096, a[8], a[9], a[10], a[11]);
        ld4g<FAST>(pA + 6144, a[12], a[13], a[14], a[15]);
        vmwait();
        f32x4 acc[4] = {Z, Z, Z, Z};
        #pragma unroll
        for (int kk = 0; kk < 16; ++kk)
            #pragma unroll
            for (int nt = 0; nt < 4; ++nt)
                acc[nt] = MFMA(a[kk], *(const bf16x8*)&sW1[(nt * 16 + kk) * 512 + lane * 8], acc[nt]);
        #pragma unroll
        for (int nt = 0; nt < 4; ++nt) {
            const int oct = 2 * (nt & 1) + (lm >> 3);
            const int base = (m * 2 + (nt >> 1)) * 512;
            #pragma unroll
            for (int r = 0; r < 4; ++r)
                bnc[base + ((q4 + r) + oct * 16) * 8 + (lm & 7)] = (bf16)eluf(acc[nt][r] + b1r[nt]);
        }
    }
    __syncthreads();
    {
        const int i = tid * 16, mm = i >> 10, rem = i & 1023;
        bf16* d = gH2 + mm * 8192 + (2 * j + (rem >> 9)) * 512 + (rem & 511);
        st8g<FAST>(d, *(const bf16x8*)&bnc[i]);
        st8g<FAST>(d + 8, *(const bf16x8*)&bnc[i + 8]);
    }
    produce(fH2, tid); ++eH2;
    consume(fH2, GSZ * eH2, tid);

    // ---- L2: k-slice = h2 @ W2s^T + b2s; build y_stage ----
    {
        bf16x8 a[16];
        const bf16* pA = gH2 + m * 8192 + lane * 8;
        ld4g<FAST>(pA, a[0], a[1], a[2], a[3]);
        ld4g<FAST>(pA + 2048, a[4], a[5], a[6], a[7]);
        ld4g<FAST>(pA + 4096, a[8], a[9], a[10], a[11]);
        ld4g<FAST>(pA + 6144, a[12], a[13], a[14], a[15]);
        vmwait();
        f32x4 kk2[2] = {Z, Z};
        #pragma unroll
        for (int kk = 0; kk < 16; ++kk)
            #pragma unroll
            for (int nt = 0; nt < 2; ++nt)
                kk2[nt] = MFMA(a[kk], *(const bf16x8*)&sW2[(nt * 16 + kk) * 512 + lane * 8], kk2[nt]);
        #pragma unroll
        for (int nt = 0; nt < 2; ++nt)
            #pragma unroll
            for (int r = 0; r < 4; ++r) kk2[nt][r] += b2r[nt];

        f32x4 yst[2];
        if constexpr (ST < 5) {
            kreg[ST][0] = kk2[0]; kreg[ST][1] = kk2[1];
            #pragma unroll
            for (int nt = 0; nt < 2; ++nt) {
                yst[nt] = yreg[nt];
                #pragma unroll
                for (int i = 0; i <= ST; ++i) {
                    const float c = DT * BROW[ST][i];
                    #pragma unroll
                    for (int r = 0; r < 4; ++r) yst[nt][r] += c * kreg[i][nt][r];
                }
            }
        } else {
            #pragma unroll
            for (int nt = 0; nt < 2; ++nt) {
                #pragma unroll
                for (int i = 0; i < 5; ++i) {
                    const float c = DT * FCF[i];
                    #pragma unroll
                    for (int r = 0; r < 4; ++r) yreg[nt][r] += c * kreg[i][nt][r];
                }
                #pragma unroll
                for (int r = 0; r < 4; ++r) yreg[nt][r] += (DT * FCF[5]) * kk2[nt][r];
                yst[nt] = yreg[nt];
            }
        }
        #pragma unroll
        for (int nt = 0; nt < 2; ++nt) {
            const int oct = 2 * nt + (lm >> 3);
            #pragma unroll
            for (int r = 0; r < 4; ++r)
                bnc[(m * 64 + (q4 + r) + oct * 16) * 8 + (lm & 7)] = (bf16)yst[nt][r];
        }
    }
    __syncthreads();
    {   // copy 8KB bounce -> gY (block's kk=j slice)
        const int i = tid * 8, mm = i >> 9, rem = i & 511;
        st8g<FAST>(gY + mm * 4096 + j * 512 + rem, *(const bf16x8*)&bnc[i]);
    }
    produce(fY, tid); ++eY;
}

template<bool FAST>
__device__ void body(const float* __restrict__ x_seq, const int* __restrict__ cidx,
                     const float* __restrict__ b_n, const float* __restrict__ b0,
                     const float* __restrict__ b1, const float* __restrict__ b2,
                     const float* __restrict__ W_dec, const float* __restrict__ b_dec,
                     char* __restrict__ ws, float* __restrict__ out, char* SM,
                     int H, int g, int j) {
    const int tid = threadIdx.x, m = tid >> 6, lane = tid & 63;
    const int lm = lane & 15, q = lane >> 4, q4 = q << 2;
    const int grow0 = g * 128;

    const bf16* W0p  = (const bf16*)(ws + WS_W0);
    const bf16* W1p  = (const bf16*)(ws + WS_W1);
    const bf16* W2p  = (const bf16*)(ws + WS_W2);
    const bf16* WhhP = (const bf16*)(ws + WS_WHH);
    const bf16* WihP = (const bf16*)(ws + WS_WIH);
    const float* bias_c = (const float*)(ws + WS_BC);
    bf16* gY  = (bf16*)(ws + WS_GY)  + (size_t)g * 32768;
    bf16* gYb = (bf16*)(ws + WS_GYB) + (size_t)g * 32768;
    bf16* gH1 = (bf16*)(ws + WS_GH1) + (size_t)g * 65536;
    bf16* gH2 = (bf16*)(ws + WS_GH2) + (size_t)g * 65536;
    unsigned* fl = (unsigned*)(ws + WS_FLG) + (size_t)g * 64;
    unsigned *fY = fl, *fH1 = fl + 16, *fH2 = fl + 32;

    bf16*  sWgt  = (bf16*)SM;                 // 128KB region (GRU slices share it)
    bf16*  bnc   = (bf16*)(SM + 131072);      // 16KB bounce
    float* bncF  = (float*)(SM + 131072);
    float* sWdec = (float*)(SM + 147456);     // 8KB
    float* sBdec = (float*)(SM + 155648);

    unsigned eY = 0, eH1 = 0, eH2 = 0;

    // ---- stage decode weights ----
    for (int i = tid; i < 2048; i += NTHR) sWdec[i] = W_dec[i];
    if (tid < 8) sBdec[tid] = b_dec[tid];

    // ---- stage GRU weight slices (sGhh @0: 6x4096, sGih @24576: 6x512) ----
    bf16* sGhh = sWgt;
    bf16* sGih = sWgt + 24576;
    for (int i = tid; i < 3072; i += NTHR) {
        const int gh = i >> 9, inner = (i & 511) << 3;
        const int c = (gh >> 1) * 16 + 2 * j + (gh & 1);
        *(bf16x8*)&sGhh[gh * 4096 + inner] = *(const bf16x8*)&WhhP[(size_t)c * 4096 + inner];
    }
    for (int i = tid; i < 384; i += NTHR) {
        const int gh = i >> 6, inner = (i & 63) << 3;
        const int c = (gh >> 1) * 16 + 2 * j + (gh & 1);
        *(bf16x8*)&sGih[gh * 512 + inner] = *(const bf16x8*)&WihP[(size_t)c * 512 + inner];
    }

    // ---- per-wave GRU gate biases ----
    float bcr[2][4], bcz[2][4], bcn[2][4], bnr[2];
    #pragma unroll
    for (int h = 0; h < 2; ++h) {
        const int F = 32 * j + 16 * h + lm;
        bnr[h] = b_n[F];
        #pragma unroll
        for (int r = 0; r < 4; ++r) {
            const int c = cidx[grow0 + 16 * m + q4 + r];
            bcr[h][r] = bias_c[(size_t)c * 768 + F];
            bcz[h][r] = bias_c[(size_t)c * 768 + 256 + F];
            bcn[h][r] = bias_c[(size_t)c * 768 + 512 + F];
        }
    }
    __syncthreads();

    // ---- h0 = 0 ----
    {
        bf16x8 zz;
        #pragma unroll
        for (int e = 0; e < 8; ++e) zz[e] = (bf16)0.f;
        const int i = tid * 8, mm = i >> 9, rem = i & 511;
        st8g<FAST>(gY + mm * 4096 + j * 512 + rem, zz);
    }
    produce(fY, tid); ++eY;

    f32x4 hreg[2] = {{0.f,0.f,0.f,0.f},{0.f,0.f,0.f,0.f}};
    const f32x4 Z = {0.f, 0.f, 0.f, 0.f};

    // ---- GRU scan ----
    for (int t = 0; t < T_SEQ; ++t) {
        consume(fY, GSZ * eY, tid);
        const bf16* hb = (t & 1) ? gYb : gY;
        bf16x8 a[8];
        const bf16* pA = hb + m * 4096 + lane * 8;
        ld4g<FAST>(pA, a[0], a[1], a[2], a[3]);
        ld4g<FAST>(pA + 2048, a[4], a[5], a[6], a[7]);
        bf16x8 ax;
        {
            const float* xp = x_seq + (((size_t)(grow0 + 16 * m + lm)) * T_SEQ + t) * 32 + 8 * q;
            f32x4 xa = *(const f32x4*)xp;
            f32x4 xb = *(const f32x4*)(xp + 4);
            #pragma unroll
            for (int e = 0; e < 4; ++e) { ax[e] = (bf16)xa[e]; ax[4 + e] = (bf16)xb[e]; }
        }
        vmwait();
        f32x4 aRZ[4] = {Z, Z, Z, Z}, aNH[2] = {Z, Z}, aNX[2] = {Z, Z};
        #pragma unroll
        for (int kk = 0; kk < 8; ++kk) {
            #pragma unroll
            for (int h = 0; h < 2; ++h) {
                aRZ[h]     = MFMA(a[kk], *(const bf16x8*)&sGhh[(0 + h) * 4096 + kk * 512 + lane * 8], aRZ[h]);
                aRZ[2 + h] = MFMA(a[kk], *(const bf16x8*)&sGhh[(2 + h) * 4096 + kk * 512 + lane * 8], aRZ[2 + h]);
                aNH[h]     = MFMA(a[kk], *(const bf16x8*)&sGhh[(4 + h) * 4096 + kk * 512 + lane * 8], aNH[h]);
            }
        }
        #pragma unroll
        for (int h = 0; h < 2; ++h) {
            aRZ[h]     = MFMA(ax, *(const bf16x8*)&sGih[(0 + h) * 512 + lane * 8], aRZ[h]);
            aRZ[2 + h] = MFMA(ax, *(const bf16x8*)&sGih[(2 + h) * 512 + lane * 8], aRZ[2 + h]);
            aNX[h]     = MFMA(ax, *(const bf16x8*)&sGih[(4 + h) * 512 + lane * 8], aNX[h]);
        }
        #pragma unroll
        for (int h = 0; h < 2; ++h) {
            const int oct = 2 * h + (lm >> 3);
            #pragma unroll
            for (int r = 0; r < 4; ++r) {
                const float rg = sigm_f(aRZ[h][r] + bcr[h][r]);
                const float zg = sigm_f(aRZ[2 + h][r] + bcz[h][r]);
                const float nn = tanh_f(aNX[h][r] + bcn[h][r] + rg * (aNH[h][r] + bnr[h]));
                const float hp = nn + zg * (hreg[h][r] - nn);
                hreg[h][r] = hp;
                bnc[(m * 64 + (q4 + r) + oct * 16) * 8 + (lm & 7)] = (bf16)hp;
            }
        }
        __syncthreads();
        {
            bf16* wb = ((t + 1) & 1) ? gYb : gY;
            const int i = tid * 8, mm = i >> 9, rem = i & 511;
            st8g<FAST>(wb + mm * 4096 + j * 512 + rem, *(const bf16x8*)&bnc[i]);
        }
        produce(fY, tid); ++eY;
    }

    // ---- stage ODE weight slices (overwrite GRU region) ----
    bf16* sW0 = sWgt;            // 16384 elems
    bf16* sW1 = sWgt + 16384;    // 32768 elems
    bf16* sW2 = sWgt + 49152;    // 16384 elems
    for (int i = tid; i < 2048; i += NTHR)
        *(bf16x8*)&sW0[i * 8] = *(const bf16x8*)&W0p[(size_t)j * 16384 + i * 8];
    for (int i = tid; i < 4096; i += NTHR)
        *(bf16x8*)&sW1[i * 8] = *(const bf16x8*)&W1p[(size_t)j * 32768 + i * 8];
    for (int i = tid; i < 2048; i += NTHR)
        *(bf16x8*)&sW2[i * 8] = *(const bf16x8*)&W2p[(size_t)j * 16384 + i * 8];

    float b0r[4], b1r[4], b2r[2];
    #pragma unroll
    for (int nt = 0; nt < 4; ++nt) {
        b0r[nt] = b0[64 * j + nt * 16 + lm];
        b1r[nt] = b1[64 * j + nt * 16 + lm];
    }
    #pragma unroll
    for (int nt = 0; nt < 2; ++nt) b2r[nt] = b2[32 * j + nt * 16 + lm];
    __syncthreads();

    f32x4 yreg[2] = {hreg[0], hreg[1]};
    f32x4 kreg[5][2];

    // ---- Neural ODE (Tsit5) + decode ----
    const int NSS = H * 10;
    for (int ss = 0; ss < NSS; ++ss) {
        consume(fY, GSZ * eY, tid);
        if (ss && (ss % 10) == 0)
            decode<FAST>(gY, sWdec, sBdec, bncF, out, tid, g, j, H, ss / 10 - 1);
        ode_stage<0, FAST>(sW0, sW1, sW2, bnc, gY, gH1, gH2, fY, fH1, fH2, b0r, b1r, b2r, yreg, kreg, tid, m, lane, j, eY, eH1, eH2);
        consume(fY, GSZ * eY, tid);
        ode_stage<1, FAST>(sW0, sW1, sW2, bnc, gY, gH1, gH2, fY, fH1, fH2, b0r, b1r, b2r, yreg, kreg, tid, m, lane, j, eY, eH1, eH2);
        consume(fY, GSZ * eY, tid);
        ode_stage<2, FAST>(sW0, sW1, sW2, bnc, gY, gH1, gH2, fY, fH1, fH2, b0r, b1r, b2r, yreg, kreg, tid, m, lane, j, eY, eH1, eH2);
        consume(fY, GSZ * eY, tid);
        ode_stage<3, FAST>(sW0, sW1, sW2, bnc, gY, gH1, gH2, fY, fH1, fH2, b0r, b1r, b2r, yreg, kreg, tid, m, lane, j, eY, eH1, eH2);
        consume(fY, GSZ * eY, tid);
        ode_stage<4, FAST>(sW0, sW1, sW2, bnc, gY, gH1, gH2, fY, fH1, fH2, b0r, b1r, b2r, yreg, kreg, tid, m, lane, j, eY, eH1, eH2);
        consume(fY, GSZ * eY, tid);
        ode_stage<5, FAST>(sW0, sW1, sW2, bnc, gY, gH1, gH2, fY, fH1, fH2, b0r, b1r, b2r, yreg, kreg, tid, m, lane, j, eY, eH1, eH2);
    }
    consume(fY, GSZ * eY, tid);
    decode<FAST>(gY, sWdec, sBdec, bncF, out, tid, g, j, H, H - 1);
}

__global__ void __launch_bounds__(NTHR, 2)
k_main(const float* __restrict__ x_seq, const int* __restrict__ cidx,
       const float* __restrict__ b_n, const float* __restrict__ b0,
       const float* __restrict__ b1, const float* __restrict__ b2,
       const float* __restrict__ W_dec, const float* __restrict__ b_dec,
       char* __restrict__ ws, float* __restrict__ out, int H) {
    __shared__ __align__(16) char SM[155712];
    const int tid = threadIdx.x, b = blockIdx.x;
    const int x8 = b & 7, rr = b >> 3, mg = rr >> 3, j = rr & 7;
    const int g = x8 * 4 + mg;

    unsigned* xmap = (unsigned*)(ws + WS_MAP);
    unsigned* gctr = (unsigned*)(ws + WS_MAP + 1024);
    unsigned xcc;
    asm volatile("s_getreg_b32 %0, hwreg(HW_REG_XCC_ID)" : "=s"(xcc));
    if (tid == 0) {
        __hip_atomic_store(&xmap[b], xcc, __ATOMIC_RELAXED, __HIP_MEMORY_SCOPE_AGENT);
        __hip_atomic_fetch_add(gctr, 1u, __ATOMIC_RELAXED, __HIP_MEMORY_SCOPE_AGENT);
        while (__hip_atomic_load(gctr, __ATOMIC_RELAXED, __HIP_MEMORY_SCOPE_AGENT) < NBLK)
            __builtin_amdgcn_s_sleep(8);
    }
    __syncthreads();
    unsigned* mapL = (unsigned*)(SM + 131072);
    if (tid < NBLK)
        mapL[tid] = __hip_atomic_load(&xmap[tid], __ATOMIC_RELAXED, __HIP_MEMORY_SCOPE_AGENT);
    __syncthreads();
    int* fastP = (int*)(SM + 155696);
    if (tid == 0) {
        const unsigned my = mapL[b];
        int cnt = 0;
        for (int i = 0; i < NBLK; ++i) cnt += (mapL[i] == my) ? 1 : 0;
        int ok = (cnt == 32) ? 1 : 0;
        for (int i = 0; i < GSZ; ++i) ok &= (mapL[x8 + 8 * (mg * 8 + i)] == my) ? 1 : 0;
        *fastP = ok;
    }
    __syncthreads();
    const int fastf = *fastP;
    __syncthreads();

    if (fastf)
        body<true>(x_seq, cidx, b_n, b0, b1, b2, W_dec, b_dec, ws, out, (char*)SM, H, g, j);
    else
        body<false>(x_seq, cidx, b_n, b0, b1, b2, W_dec, b_dec, ws, out, (char*)SM, H, g, j);
}

// Pack fp32 weight [OUT][Ksrc] (cols koff..koff+K) into MFMA-fragment order bf16:
// frag f = c*(K/32)+kk; lane's 8 elems = row c*16+(lane&15), k = kk*32+(lane>>4)*8+j
__global__ void k_pack(const float* __restrict__ src, bf16* __restrict__ dst,
                       int OUT, int K, int Ksrc, int koff) {
    const int total = (OUT * K) >> 3;
    for (int gg = blockIdx.x * blockDim.x + threadIdx.x; gg < total; gg += gridDim.x * blockDim.x) {
        const int lane = gg & 63, f = gg >> 6;
        const int KK = K >> 5;
        const int kk = f % KK, c = f / KK;
        const int col = c * 16 + (lane & 15);
        const int k0 = kk * 32 + ((lane >> 4) << 3);
        bf16x8 o;
        #pragma unroll
        for (int jj = 0; jj < 8; ++jj) o[jj] = (bf16)src[(size_t)col * Ksrc + koff + k0 + jj];
        *(bf16x8*)&dst[(size_t)gg * 8] = o;
    }
}

__global__ void k_bias(const float* __restrict__ W_ih, const float* __restrict__ b_ih,
                       float* __restrict__ bias_c) {
    const int i = blockIdx.x * blockDim.x + threadIdx.x;
    if (i < 64 * 768) {
        const int c = i / 768, n = i - c * 768;
        bias_c[i] = W_ih[(size_t)n * 96 + 32 + c] + b_ih[n];
    }
}

extern "C" void kernel_launch(void* const* d_in, const int* in_sizes, int n_in,
                              void* d_out, int out_size, void* d_ws, size_t ws_size,
                              hipStream_t stream) {
    const float* x_seq = (const float*)d_in[0];
    const int*   cidx  = (const int*)d_in[1];
    const float* W_ih  = (const float*)d_in[3];
    const float* W_hh  = (const float*)d_in[4];
    const float* b_ih  = (const float*)d_in[5];
    const float* b_n   = (const float*)d_in[6];
    const float* W0    = (const float*)d_in[7];
    const float* b0    = (const float*)d_in[8];
    const float* W1    = (const float*)d_in[9];
    const float* b1    = (const float*)d_in[10];
    const float* W2    = (const float*)d_in[11];
    const float* b2    = (const float*)d_in[12];
    const float* W_dec = (const float*)d_in[13];
    const float* b_dec = (const float*)d_in[14];
    float* out = (float*)d_out;
    const int H = out_size / (B_TOT * NT_OUT);
    char* ws = (char*)d_ws;

    // zero flags + xcd map + grid counter (re-done every launch -> graph-replay safe)
    hipMemsetAsync(ws + WS_FLG, 0, 16384, stream);

    k_pack<<<64, 256, 0, stream>>>(W0, (bf16*)(ws + WS_W0), 512, 256, 256, 0);
    k_pack<<<128, 256, 0, stream>>>(W1, (bf16*)(ws + WS_W1), 512, 512, 512, 0);
    k_pack<<<64, 256, 0, stream>>>(W2, (bf16*)(ws + WS_W2), 256, 512, 512, 0);
    k_pack<<<96, 256, 0, stream>>>(W_hh, (bf16*)(ws + WS_WHH), 768, 256, 256, 0);
    k_pack<<<12, 256, 0, stream>>>(W_ih, (bf16*)(ws + WS_WIH), 768, 32, 96, 0);
    k_bias<<<(64 * 768 + 255) / 256, 256, 0, stream>>>(W_ih, b_ih, (float*)(ws + WS_BC));

    k_main<<<NBLK, NTHR, 0, stream>>>(x_seq, cidx, b_n, b0, b1, b2, W_dec, b_dec,
                                      ws, out, H);
}